// Round 7
// baseline (144.080 us; speedup 1.0000x reference)
//
#include <hip/hip_runtime.h>

typedef unsigned short u16;
typedef __attribute__((ext_vector_type(8))) short short8;
typedef __attribute__((ext_vector_type(4))) float f32x4;

#define NF 2
#define NV 4
#define FV 8
#define NE 2048
#define NIN 512
#define NOUT 512
#define NM 514

// ws layout (bytes)
#define WS_P1      0u
#define WS_P2      2048u
#define WS_P3      3072u
#define WS_SCALE   4224u
#define WS_G       6272u
#define WS_GN      8448u
#define WS_ETA     10496u
#define WS_BIASZ   18688u
#define WS_BIAST   35072u
#define WS_DENP    51456u
#define WS_PMIN    182528u
#define WS_PSUM    313600u
#define WS_ABF     444672u
#define WS_BZT     17221888u
#define WS_BTT     21416192u

__constant__ float c_etas[4][4] = {
    {0.05f, 0.90f, 0.20f, 8.0f},
    {0.10f, 0.80f, 0.30f, 5.0f},
    {0.00f, 1.00f, 0.25f, 10.0f},
    {0.15f, 0.70f, 0.15f, 6.0f}};

__device__ __forceinline__ u16 f2bf(float x) {
    unsigned u = __float_as_uint(x);
    unsigned r = (u + 0x7fffu + ((u >> 16) & 1u)) >> 16;
    return (u16)r;
}

__device__ __forceinline__ void gll16(const void* g, void* l) {
    __builtin_amdgcn_global_load_lds((__attribute__((address_space(1))) void*)g,
                                     (__attribute__((address_space(3))) void*)l,
                                     16, 0, 0);
}

// ---- kA: per-column partial min/sum of g_init over 33-row stripes (16 blocks);
// block 0 zeroes atomic slots + G ----
__global__ void kA_part(const float* __restrict__ theta_, float* __restrict__ pmin,
                        float* __restrict__ psum, float* __restrict__ wszero) {
    int t = threadIdx.x;
    if (blockIdx.x == 0) {
        for (int i = t; i < 2112; i += 256) wszero[i] = 0.f;
    }
    int n2 = t * 2;
    int r0 = blockIdx.x * 33;
    float mn0 = 3.4e38f, mn1 = 3.4e38f, s0 = 0.f, s1 = 0.f;
    int rend = r0 + 33;
    if (rend > NM) rend = NM;
    for (int r = r0; r < rend; r++) {
        float2 v = *(const float2*)(theta_ + r * NOUT + n2);
        float a0 = fabsf(fminf(fmaxf(v.x, -10.f), 10.f));
        float a1 = fabsf(fminf(fmaxf(v.y, -10.f), 10.f));
        mn0 = fminf(mn0, a0); mn1 = fminf(mn1, a1);
        s0 += a0; s1 += a1;
    }
    *(float2*)(pmin + blockIdx.x * NOUT + n2) = make_float2(mn0, mn1);
    *(float2*)(psum + blockIdx.x * NOUT + n2) = make_float2(s0, s1);
}

// ---- k_wmat3: B-matrices + denom partials + G[m] atomics + inline scale;
// mt==0 blocks emit Gn/eta4 (redundant identical writes across fv: benign) ----
__global__ void k_wmat3(const float* __restrict__ theta_,
                        const float* __restrict__ pmin, const float* __restrict__ psum,
                        const float* __restrict__ coeff, const float* __restrict__ gumb,
                        const float* __restrict__ noise,
                        u16* __restrict__ BzT, u16* __restrict__ BtT,
                        float* __restrict__ bias_z, float* __restrict__ bias_t,
                        float* __restrict__ denomp, float* __restrict__ G,
                        float* __restrict__ Gn, float4* __restrict__ eta4) {
    const int nt = blockIdx.x, mt = blockIdx.y, fv = blockIdx.z;  // 8,8,8
    const int t = threadIdx.x;
    const int nq = t & 15, mr = t >> 4;
    const int nb = nt * 64 + nq * 4;
    __shared__ u16 Wl[64][72];
    __shared__ u16 Sl[64][72];
    __shared__ float4 red[16][17];
    float4 mn4 = {3.4e38f, 3.4e38f, 3.4e38f, 3.4e38f};
#pragma unroll
    for (int i = 0; i < 16; i++) {
        float4 v = *(const float4*)(pmin + i * NOUT + nb);
        mn4.x = fminf(mn4.x, v.x); mn4.y = fminf(mn4.y, v.y);
        mn4.z = fminf(mn4.z, v.z); mn4.w = fminf(mn4.w, v.w);
    }
    float4 sc4 = {1e-4f / mn4.x, 1e-4f / mn4.y, 1e-4f / mn4.z, 1e-4f / mn4.w};
    float4 dacc = {0.f, 0.f, 0.f, 0.f};
#pragma unroll
    for (int i = 0; i < 4; i++) {
        int ml = mr + i * 16;
        int m = mt * 64 + ml;
        float4 th4 = *(const float4*)(theta_ + m * NOUT + nb);
        float4 no4 = *(const float4*)(noise + (fv * NM + m) * NOUT + nb);
        ushort4 wv, sv;
        float gs = 0.f;
#define WCOMP(c, fld) { float fac = no4.c * 0.2f + 0.9f; \
                        float thc = fminf(fmaxf(th4.c, -10.f), 10.f); \
                        float gi = fabsf(thc); \
                        float tht = (gi < 0.01f) ? 0.f : thc; \
                        float th = tht * fac; \
                        wv.fld = f2bf(th); \
                        sv.fld = f2bf(((th >= 0.f) ? gi : -gi) * sc4.c); \
                        gs += gi * sc4.c; \
                        dacc.c += fabsf(th); }
        WCOMP(x, x) WCOMP(y, y) WCOMP(z, z) WCOMP(w, w)
#undef WCOMP
        *(ushort4*)(&Wl[ml][nq * 4]) = wv;
        *(ushort4*)(&Sl[ml][nq * 4]) = sv;
        if (fv == 0) {
            gs += __shfl_xor(gs, 1);
            gs += __shfl_xor(gs, 2);
            gs += __shfl_xor(gs, 4);
            gs += __shfl_xor(gs, 8);
            if (nq == 0) atomicAdd(&G[m], gs);
        }
    }
    red[mr][nq] = dacc;
    __syncthreads();
    if (t < 16) {
        float4 s = red[0][t];
#pragma unroll
        for (int r = 1; r < 16; r++) {
            float4 v = red[r][t];
            s.x += v.x; s.y += v.y; s.z += v.z; s.w += v.w;
        }
        *(float4*)(denomp + (mt * 8 + fv) * NOUT + nt * 64 + t * 4) = s;
    }
    const int mb = (t & 15) * 4;
#pragma unroll
    for (int r = 0; r < 4; r++) {
        int nl = (t >> 4) + r * 16;
        ushort4 wv, sv;
        wv.x = Wl[mb][nl]; wv.y = Wl[mb + 1][nl]; wv.z = Wl[mb + 2][nl]; wv.w = Wl[mb + 3][nl];
        sv.x = Sl[mb][nl]; sv.y = Sl[mb + 1][nl]; sv.z = Sl[mb + 2][nl]; sv.w = Sl[mb + 3][nl];
        int gidx = (fv * NOUT + nt * 64 + nl) * NIN + mt * 64 + mb;
        *(ushort4*)(BzT + gidx) = wv;
        *(ushort4*)(BtT + gidx) = sv;
    }
    if (mt == 0 && t < 64) {
        int n = nt * 64 + t;
        float mn = 3.4e38f, s = 0.f;
#pragma unroll
        for (int i = 0; i < 16; i++) {
            mn = fminf(mn, pmin[i * NOUT + n]);
            s += psum[i * NOUT + n];
        }
        float sc = 1e-4f / mn;
        float fac = noise[(fv * NM + 512) * NOUT + n] * 0.2f + 0.9f;
        float thc = fminf(fmaxf(theta_[512 * NOUT + n], -10.f), 10.f);
        float gi = fabsf(thc);
        float tht = (gi < 0.01f) ? 0.f : thc;
        float th = tht * fac;
        bias_z[fv * NOUT + n] = th;
        bias_t[fv * NOUT + n] = ((th >= 0.f) ? gi : -gi) * sc;
        if (fv == 0) {
            float gsb = gi * sc;
            for (int off = 32; off > 0; off >>= 1) gsb += __shfl_down(gsb, off);
            if (t == 0) atomicAdd(&G[512], gsb);
        }
        Gn[n] = sc * s;
        float best = -1e30f;
        int bi = 0;
#pragma unroll
        for (int i = 0; i < 4; i++) {
            float c = fminf(fmaxf(coeff[i * NOUT + n], -1.f), 1.f);
            float u = gumb[i * NOUT + n];
            float g = -logf(-logf(u + 1e-20f) + 1e-20f);
            float v = c + g;
            if (v > best) { best = v; bi = i; }
        }
        eta4[n] = make_float4(c_etas[bi][0], c_etas[bi][1], c_etas[bi][2], c_etas[bi][3]);
    }
}

// ---- k_prepA: convert A to bf16 + p1 partial (R2-proven) ----
__global__ void k_prepA(const float* __restrict__ a_prev, const float* __restrict__ G,
                        u16* __restrict__ Abf, float* __restrict__ p1slot) {
    int t = threadIdx.x;
    float acc = 0.f;
#pragma unroll
    for (int i = 0; i < 4; i++) {
        int idx = (i * 2048 + blockIdx.x) * 256 + t;
        float4 v = ((const float4*)a_prev)[idx];
        int k = (idx & 127) << 2;
        float4 g4 = *((const float4*)(G + k));
        acc += v.x * v.x * g4.x + v.y * v.y * g4.y + v.z * v.z * g4.z + v.w * v.w * g4.w;
        ushort4 o;
        o.x = f2bf(v.x); o.y = f2bf(v.y); o.z = f2bf(v.z); o.w = f2bf(v.w);
        ((ushort4*)Abf)[idx] = o;
    }
    for (int off = 32; off > 0; off >>= 1) acc += __shfl_down(acc, off);
    __shared__ float red[4];
    int lane = t & 63, wv = t >> 6;
    if (lane == 0) red[wv] = acc;
    __syncthreads();
    if (t == 0)
        atomicAdd(&p1slot[(blockIdx.x & 63) * 8], red[0] + red[1] + red[2] + red[3]);
}

// ---- k_gemm: 64x128 tile, 40 KB LDS, 1024 blocks (~3-4/CU), same 2-barrier
// K-loop as R2 but with higher occupancy so the vmcnt(0)+barrier drain of one
// block overlaps the MFMA phases of the others (R1/R5 evidence: occupancy is
// this kernel's dominant lever; acc halves -> ~170 unified regs @ (256,3)). ----
__global__ __launch_bounds__(256, 3) void k_gemm(
    const u16* __restrict__ Abf, const u16* __restrict__ BzT, const u16* __restrict__ BtT,
    const float* __restrict__ bias_z, const float* __restrict__ bias_t,
    const float* __restrict__ Gn, const float4* __restrict__ eta4,
    const float* __restrict__ theta_, const float* __restrict__ noise,
    const float* __restrict__ denomp,
    float* __restrict__ out, float* __restrict__ p2slot, float* __restrict__ p3slot) {
    __shared__ alignas(16) u16 As[64 * 64];    // 8 KB
    __shared__ alignas(16) u16 Bzs[128 * 64];  // 16 KB
    __shared__ alignas(16) u16 Bts[128 * 64];  // 16 KB
    const int tid = threadIdx.x;
    const int lane = tid & 63;
    const int wv = tid >> 6;
    const int wr = wv >> 1, wc = wv & 1;     // wr: e-half (32 rows), wc: n-half (64 cols)
    const int b = blockIdx.x;
    const int fv = b & 7;                     // XCD-local fv slice
    const int kk = b >> 3;                    // 0..127
    const int n0 = (kk & 3) * 128;
    const int e0 = (kk >> 2) * 64;            // 32 e-tiles of 64

    const u16* Ag = Abf + (fv * NE + e0) * NIN;
    const u16* Bzg = BzT + (fv * NOUT + n0) * NIN;
    const u16* Btg = BtT + (fv * NOUT + n0) * NIN;

    f32x4 accz[2][4], acct[2][4];
#pragma unroll
    for (int i = 0; i < 2; i++)
#pragma unroll
        for (int j = 0; j < 4; j++) {
            f32x4 zz = {0.f, 0.f, 0.f, 0.f};
            accz[i][j] = zz;
            acct[i][j] = zz;
        }

    const int srow = tid >> 3;                        // 0..31 rows per issue
    const int swz = (((tid & 7) ^ (srow & 7))) * 8;   // pre-swizzled global slot

    for (int k0 = 0; k0 < 512; k0 += 64) {
        // A: 64 rows x 64 k = 2 issues of 256x16B
#pragma unroll
        for (int h = 0; h < 2; h++) {
            int so = (h * 32 + srow) * 512 + k0 + swz;
            gll16(Ag + so, (u16*)As + h * 2048 + tid * 8);
        }
        // Bz/Bt: 128 rows x 64 k = 4 issues each
#pragma unroll
        for (int i = 0; i < 4; i++) {
            int so = (i * 32 + srow) * 512 + k0 + swz;
            int dof = i * 2048 + tid * 8;
            gll16(Bzg + so, (u16*)Bzs + dof);
            gll16(Btg + so, (u16*)Bts + dof);
        }
        __builtin_amdgcn_s_waitcnt(0);
        __syncthreads();
        const int rA = wr * 32 + (lane & 15);
        const int rB = wc * 64 + (lane & 15);
#pragma unroll
        for (int s = 0; s < 2; s++) {
            const int ca = ((s * 4 + (lane >> 4)) ^ (lane & 7)) * 8;
            short8 af[2], bzf[4], btf[4];
#pragma unroll
            for (int i = 0; i < 2; i++) af[i] = *(const short8*)(As + (rA + i * 16) * 64 + ca);
#pragma unroll
            for (int j = 0; j < 4; j++) {
                bzf[j] = *(const short8*)(Bzs + (rB + j * 16) * 64 + ca);
                btf[j] = *(const short8*)(Bts + (rB + j * 16) * 64 + ca);
            }
#pragma unroll
            for (int i = 0; i < 2; i++)
#pragma unroll
                for (int j = 0; j < 4; j++) {
                    accz[i][j] = __builtin_amdgcn_mfma_f32_16x16x32_bf16(af[i], bzf[j], accz[i][j], 0, 0, 0);
                    acct[i][j] = __builtin_amdgcn_mfma_f32_16x16x32_bf16(af[i], btf[j], acct[i][j], 0, 0, 0);
                }
        }
        __syncthreads();
    }

    float p2 = 0.f, p3 = 0.f;
    const int col = lane & 15;
    const int rowq = (lane >> 4) * 4;
#pragma unroll
    for (int j = 0; j < 4; j++) {
        int n = n0 + wc * 64 + j * 16 + col;
        float dsum = 1e-10f;
#pragma unroll
        for (int mc = 0; mc < 8; mc++) dsum += denomp[(mc * 8 + fv) * NOUT + n];
#pragma unroll
        for (int mx = 512; mx < 514; mx++) {
            float fac = noise[(fv * NM + mx) * NOUT + n] * 0.2f + 0.9f;
            float thc = fminf(fmaxf(theta_[mx * NOUT + n], -10.f), 10.f);
            float tht = (fabsf(thc) < 0.01f) ? 0.f : thc;
            dsum += fabsf(tht * fac);
        }
        float rdv = 1.f / dsum;
        float bz = bias_z[fv * NOUT + n];
        float bt = bias_t[fv * NOUT + n];
        float gnv = Gn[n];
        float4 e4 = eta4[n];
#pragma unroll
        for (int i = 0; i < 2; i++) {
            int ebase = e0 + wr * 32 + i * 16 + rowq;
#pragma unroll
            for (int r = 0; r < 4; r++) {
                float z = (accz[i][j][r] + bz) * rdv;
                float t = acct[i][j][r] + bt;
                p2 += z * t;
                p3 += z * z * gnv;
                float x = (z - e4.z) * e4.w;
                float ex = __expf(2.f * x);
                float th = 1.f - 2.f / (ex + 1.f);
                out[(fv * NE + ebase + r) * NOUT + n] = e4.x + e4.y * th;
            }
        }
    }
    for (int off = 32; off > 0; off >>= 1) {
        p2 += __shfl_down(p2, off);
        p3 += __shfl_down(p3, off);
    }
    __shared__ float r2[4], r3[4];
    if (lane == 0) { r2[wv] = p2; r3[wv] = p3; }
    __syncthreads();
    if (tid == 0) {
        int slot = (b & 31) * 8;
        atomicAdd(&p2slot[slot], r2[0] + r2[1] + r2[2] + r2[3]);
        atomicAdd(&p3slot[slot], r3[0] + r3[1] + r3[2] + r3[3]);
    }
}

// ---- k_final: sum slots, combine power terms ----
__global__ void k_final(const float* __restrict__ p1s, const float* __restrict__ p2s,
                        const float* __restrict__ p3s, const float* __restrict__ G,
                        float* __restrict__ out) {
    int t = threadIdx.x;  // 64
    float s1 = p1s[t * 8];
    float s2 = (t < 32) ? p2s[t * 8] : 0.f;
    float s3 = (t < 32) ? p3s[t * 8] : 0.f;
    for (int off = 32; off > 0; off >>= 1) {
        s1 += __shfl_down(s1, off);
        s2 += __shfl_down(s2, off);
        s3 += __shfl_down(s3, off);
    }
    if (t == 0) {
        float mp = (s1 + 16384.f * G[512] - 2.f * s2 + s3) * (1.f / 16384.f);
        out[8388608] = mp;
    }
}

extern "C" void kernel_launch(void* const* d_in, const int* in_sizes, int n_in,
                              void* d_out, int out_size, void* d_ws, size_t ws_size,
                              hipStream_t stream) {
    const float* a_prev = (const float*)d_in[0];
    const float* theta_ = (const float*)d_in[1];
    const float* coeff = (const float*)d_in[2];
    const float* noise = (const float*)d_in[3];
    const float* gumb = (const float*)d_in[4];
    float* out = (float*)d_out;
    char* w = (char*)d_ws;
    float* p1s = (float*)(w + WS_P1);
    float* p2s = (float*)(w + WS_P2);
    float* p3s = (float*)(w + WS_P3);
    float* G = (float*)(w + WS_G);
    float* Gn = (float*)(w + WS_GN);
    float4* eta4 = (float4*)(w + WS_ETA);
    float* bias_z = (float*)(w + WS_BIASZ);
    float* bias_t = (float*)(w + WS_BIAST);
    float* denomp = (float*)(w + WS_DENP);
    float* pmin = (float*)(w + WS_PMIN);
    float* psum = (float*)(w + WS_PSUM);
    u16* Abf = (u16*)(w + WS_ABF);
    u16* BzT = (u16*)(w + WS_BZT);
    u16* BtT = (u16*)(w + WS_BTT);

    kA_part<<<16, 256, 0, stream>>>(theta_, pmin, psum, (float*)w);
    k_wmat3<<<dim3(8, 8, FV), 256, 0, stream>>>(theta_, pmin, psum, coeff, gumb, noise,
                                                BzT, BtT, bias_z, bias_t, denomp, G,
                                                Gn, eta4);
    k_prepA<<<2048, 256, 0, stream>>>(a_prev, G, Abf, p1s);
    k_gemm<<<1024, 256, 0, stream>>>(Abf, BzT, BtT, bias_z, bias_t, Gn, eta4,
                                     theta_, noise, denomp, out, p2s, p3s);
    k_final<<<1, 64, 0, stream>>>(p1s, p2s, p3s, G, out);
}

// Round 8
// 139.769 us; speedup vs baseline: 1.0308x; 1.0308x over previous
//
#include <hip/hip_runtime.h>

typedef unsigned short u16;
typedef __attribute__((ext_vector_type(8))) short short8;
typedef __attribute__((ext_vector_type(4))) float f32x4;

#define NF 2
#define NV 4
#define FV 8
#define NE 2048
#define NIN 512
#define NOUT 512
#define NM 514

// ws layout (bytes)
#define WS_P1      0u
#define WS_P2      2048u
#define WS_P3      3072u
#define WS_SCALE   4224u
#define WS_G       6272u
#define WS_GN      8448u
#define WS_ETA     10496u
#define WS_BIASZ   18688u
#define WS_BIAST   35072u
#define WS_DENP    51456u
#define WS_PMIN    182528u
#define WS_PSUM    313600u
#define WS_ABF     444672u
#define WS_BZT     17221888u
#define WS_BTT     21416192u
#define WS_RDV     25610496u  // 8*512 f = 16 KB (written by prepA blks 0-7)
#define WS_EBZ     25626880u  // 8*512 f = 16 KB

__constant__ float c_etas[4][4] = {
    {0.05f, 0.90f, 0.20f, 8.0f},
    {0.10f, 0.80f, 0.30f, 5.0f},
    {0.00f, 1.00f, 0.25f, 10.0f},
    {0.15f, 0.70f, 0.15f, 6.0f}};

__device__ __forceinline__ u16 f2bf(float x) {
    unsigned u = __float_as_uint(x);
    unsigned r = (u + 0x7fffu + ((u >> 16) & 1u)) >> 16;
    return (u16)r;
}

__device__ __forceinline__ void gll16(const void* g, void* l) {
    __builtin_amdgcn_global_load_lds((__attribute__((address_space(1))) void*)g,
                                     (__attribute__((address_space(3))) void*)l,
                                     16, 0, 0);
}

// ---- kA: per-column partial min/sum of g_init over 33-row stripes (16 blocks);
// block 0 zeroes atomic slots + G ----
__global__ void kA_part(const float* __restrict__ theta_, float* __restrict__ pmin,
                        float* __restrict__ psum, float* __restrict__ wszero) {
    int t = threadIdx.x;
    if (blockIdx.x == 0) {
        for (int i = t; i < 2112; i += 256) wszero[i] = 0.f;
    }
    int n2 = t * 2;
    int r0 = blockIdx.x * 33;
    float mn0 = 3.4e38f, mn1 = 3.4e38f, s0 = 0.f, s1 = 0.f;
    int rend = r0 + 33;
    if (rend > NM) rend = NM;
    for (int r = r0; r < rend; r++) {
        float2 v = *(const float2*)(theta_ + r * NOUT + n2);
        float a0 = fabsf(fminf(fmaxf(v.x, -10.f), 10.f));
        float a1 = fabsf(fminf(fmaxf(v.y, -10.f), 10.f));
        mn0 = fminf(mn0, a0); mn1 = fminf(mn1, a1);
        s0 += a0; s1 += a1;
    }
    *(float2*)(pmin + blockIdx.x * NOUT + n2) = make_float2(mn0, mn1);
    *(float2*)(psum + blockIdx.x * NOUT + n2) = make_float2(s0, s1);
}

// ---- k_wmat3: B-matrices + denom partials + G[m] atomics + inline scale;
// mt==0 blocks emit Gn/eta4 (redundant identical writes across fv: benign) ----
__global__ void k_wmat3(const float* __restrict__ theta_,
                        const float* __restrict__ pmin, const float* __restrict__ psum,
                        const float* __restrict__ coeff, const float* __restrict__ gumb,
                        const float* __restrict__ noise,
                        u16* __restrict__ BzT, u16* __restrict__ BtT,
                        float* __restrict__ bias_z, float* __restrict__ bias_t,
                        float* __restrict__ denomp, float* __restrict__ G,
                        float* __restrict__ Gn, float4* __restrict__ eta4) {
    const int nt = blockIdx.x, mt = blockIdx.y, fv = blockIdx.z;  // 8,8,8
    const int t = threadIdx.x;
    const int nq = t & 15, mr = t >> 4;
    const int nb = nt * 64 + nq * 4;
    __shared__ u16 Wl[64][72];
    __shared__ u16 Sl[64][72];
    __shared__ float4 red[16][17];
    float4 mn4 = {3.4e38f, 3.4e38f, 3.4e38f, 3.4e38f};
#pragma unroll
    for (int i = 0; i < 16; i++) {
        float4 v = *(const float4*)(pmin + i * NOUT + nb);
        mn4.x = fminf(mn4.x, v.x); mn4.y = fminf(mn4.y, v.y);
        mn4.z = fminf(mn4.z, v.z); mn4.w = fminf(mn4.w, v.w);
    }
    float4 sc4 = {1e-4f / mn4.x, 1e-4f / mn4.y, 1e-4f / mn4.z, 1e-4f / mn4.w};
    float4 dacc = {0.f, 0.f, 0.f, 0.f};
#pragma unroll
    for (int i = 0; i < 4; i++) {
        int ml = mr + i * 16;
        int m = mt * 64 + ml;
        float4 th4 = *(const float4*)(theta_ + m * NOUT + nb);
        float4 no4 = *(const float4*)(noise + (fv * NM + m) * NOUT + nb);
        ushort4 wv, sv;
        float gs = 0.f;
#define WCOMP(c, fld) { float fac = no4.c * 0.2f + 0.9f; \
                        float thc = fminf(fmaxf(th4.c, -10.f), 10.f); \
                        float gi = fabsf(thc); \
                        float tht = (gi < 0.01f) ? 0.f : thc; \
                        float th = tht * fac; \
                        wv.fld = f2bf(th); \
                        sv.fld = f2bf(((th >= 0.f) ? gi : -gi) * sc4.c); \
                        gs += gi * sc4.c; \
                        dacc.c += fabsf(th); }
        WCOMP(x, x) WCOMP(y, y) WCOMP(z, z) WCOMP(w, w)
#undef WCOMP
        *(ushort4*)(&Wl[ml][nq * 4]) = wv;
        *(ushort4*)(&Sl[ml][nq * 4]) = sv;
        if (fv == 0) {
            gs += __shfl_xor(gs, 1);
            gs += __shfl_xor(gs, 2);
            gs += __shfl_xor(gs, 4);
            gs += __shfl_xor(gs, 8);
            if (nq == 0) atomicAdd(&G[m], gs);
        }
    }
    red[mr][nq] = dacc;
    __syncthreads();
    if (t < 16) {
        float4 s = red[0][t];
#pragma unroll
        for (int r = 1; r < 16; r++) {
            float4 v = red[r][t];
            s.x += v.x; s.y += v.y; s.z += v.z; s.w += v.w;
        }
        *(float4*)(denomp + (mt * 8 + fv) * NOUT + nt * 64 + t * 4) = s;
    }
    const int mb = (t & 15) * 4;
#pragma unroll
    for (int r = 0; r < 4; r++) {
        int nl = (t >> 4) + r * 16;
        ushort4 wv, sv;
        wv.x = Wl[mb][nl]; wv.y = Wl[mb + 1][nl]; wv.z = Wl[mb + 2][nl]; wv.w = Wl[mb + 3][nl];
        sv.x = Sl[mb][nl]; sv.y = Sl[mb + 1][nl]; sv.z = Sl[mb + 2][nl]; sv.w = Sl[mb + 3][nl];
        int gidx = (fv * NOUT + nt * 64 + nl) * NIN + mt * 64 + mb;
        *(ushort4*)(BzT + gidx) = wv;
        *(ushort4*)(BtT + gidx) = sv;
    }
    if (mt == 0 && t < 64) {
        int n = nt * 64 + t;
        float mn = 3.4e38f, s = 0.f;
#pragma unroll
        for (int i = 0; i < 16; i++) {
            mn = fminf(mn, pmin[i * NOUT + n]);
            s += psum[i * NOUT + n];
        }
        float sc = 1e-4f / mn;
        float fac = noise[(fv * NM + 512) * NOUT + n] * 0.2f + 0.9f;
        float thc = fminf(fmaxf(theta_[512 * NOUT + n], -10.f), 10.f);
        float gi = fabsf(thc);
        float tht = (gi < 0.01f) ? 0.f : thc;
        float th = tht * fac;
        bias_z[fv * NOUT + n] = th;
        bias_t[fv * NOUT + n] = ((th >= 0.f) ? gi : -gi) * sc;
        if (fv == 0) {
            float gsb = gi * sc;
            for (int off = 32; off > 0; off >>= 1) gsb += __shfl_down(gsb, off);
            if (t == 0) atomicAdd(&G[512], gsb);
        }
        Gn[n] = sc * s;
        float best = -1e30f;
        int bi = 0;
#pragma unroll
        for (int i = 0; i < 4; i++) {
            float c = fminf(fmaxf(coeff[i * NOUT + n], -1.f), 1.f);
            float u = gumb[i * NOUT + n];
            float g = -logf(-logf(u + 1e-20f) + 1e-20f);
            float v = c + g;
            if (v > best) { best = v; bi = i; }
        }
        eta4[n] = make_float4(c_etas[bi][0], c_etas[bi][1], c_etas[bi][2], c_etas[bi][3]);
    }
}

// ---- k_prepA: A->bf16 + p1 partial; blocks 0-7 also build the rdv/ebz tables
// (denomp complete + L2-hot after wmat3; kernel boundary orders vs gemm) ----
__global__ void k_prepA(const float* __restrict__ a_prev, const float* __restrict__ G,
                        const float* __restrict__ denomp, const float* __restrict__ noise,
                        const float* __restrict__ theta_, const float* __restrict__ bias_z,
                        u16* __restrict__ Abf, float* __restrict__ p1slot,
                        float* __restrict__ rdvt, float* __restrict__ ebzt) {
    int t = threadIdx.x;
    if (blockIdx.x < 8) {
        int fvb = blockIdx.x;
        for (int n = t; n < NOUT; n += 256) {
            float dsum = 1e-10f;
#pragma unroll
            for (int mc = 0; mc < 8; mc++) dsum += denomp[(mc * 8 + fvb) * NOUT + n];
#pragma unroll
            for (int mx = 512; mx < 514; mx++) {
                float fac = noise[(fvb * NM + mx) * NOUT + n] * 0.2f + 0.9f;
                float thc = fminf(fmaxf(theta_[mx * NOUT + n], -10.f), 10.f);
                float tht = (fabsf(thc) < 0.01f) ? 0.f : thc;
                dsum += fabsf(tht * fac);
            }
            float rdv = 1.f / dsum;
            rdvt[fvb * NOUT + n] = rdv;
            ebzt[fvb * NOUT + n] = bias_z[fvb * NOUT + n] * rdv;
        }
    }
    float acc = 0.f;
#pragma unroll
    for (int i = 0; i < 4; i++) {
        int idx = (i * 2048 + blockIdx.x) * 256 + t;
        float4 v = ((const float4*)a_prev)[idx];
        int k = (idx & 127) << 2;
        float4 g4 = *((const float4*)(G + k));
        acc += v.x * v.x * g4.x + v.y * v.y * g4.y + v.z * v.z * g4.z + v.w * v.w * g4.w;
        ushort4 o;
        o.x = f2bf(v.x); o.y = f2bf(v.y); o.z = f2bf(v.z); o.w = f2bf(v.w);
        ((ushort4*)Abf)[idx] = o;
    }
    for (int off = 32; off > 0; off >>= 1) acc += __shfl_down(acc, off);
    __shared__ float red[4];
    int lane = t & 63, wv = t >> 6;
    if (lane == 0) red[wv] = acc;
    __syncthreads();
    if (t == 0)
        atomicAdd(&p1slot[(blockIdx.x & 63) * 8], red[0] + red[1] + red[2] + red[3]);
}

// ---- k_gemm: R2-proven structure (128x128, 48 KB LDS, 2-barrier) with a
// slimmed epilogue: z = fma(accz, rdv[fv][n], ebz[fv][n]) — drops 48 scattered
// loads + divide chain per thread (R5 measured epilogue ~46% of kernel). ----
__global__ __launch_bounds__(256, 2) void k_gemm(
    const u16* __restrict__ Abf, const u16* __restrict__ BzT, const u16* __restrict__ BtT,
    const float* __restrict__ rdvt, const float* __restrict__ ebzt,
    const float* __restrict__ bias_t, const float* __restrict__ Gn,
    const float4* __restrict__ eta4,
    float* __restrict__ out, float* __restrict__ p2slot, float* __restrict__ p3slot) {
    __shared__ alignas(16) u16 As[128 * 64];
    __shared__ alignas(16) u16 Bzs[128 * 64];
    __shared__ alignas(16) u16 Bts[128 * 64];
    const int tid = threadIdx.x;
    const int lane = tid & 63;
    const int wv = tid >> 6;
    const int wr = wv >> 1, wc = wv & 1;
    const int b = blockIdx.x;
    const int fv = b & 7;
    const int kk = b >> 3;
    const int n0 = (kk & 3) * 128;
    const int e0 = (kk >> 2) * 128;

    const u16* Ag = Abf + (fv * NE + e0) * NIN;
    const u16* Bzg = BzT + (fv * NOUT + n0) * NIN;
    const u16* Btg = BtT + (fv * NOUT + n0) * NIN;

    f32x4 accz[4][4], acct[4][4];
#pragma unroll
    for (int i = 0; i < 4; i++)
#pragma unroll
        for (int j = 0; j < 4; j++) {
            f32x4 zz = {0.f, 0.f, 0.f, 0.f};
            accz[i][j] = zz;
            acct[i][j] = zz;
        }

    const int srow = tid >> 3;
    const int swz = (((tid & 7) ^ (srow & 7))) * 8;

    for (int k0 = 0; k0 < 512; k0 += 64) {
#pragma unroll
        for (int i = 0; i < 4; i++) {
            int so = (i * 32 + srow) * 512 + k0 + swz;
            int dof = i * 2048 + tid * 8;
            gll16(Ag + so, (u16*)As + dof);
            gll16(Bzg + so, (u16*)Bzs + dof);
            gll16(Btg + so, (u16*)Bts + dof);
        }
        __builtin_amdgcn_s_waitcnt(0);
        __syncthreads();
        const int rA = wr * 64 + (lane & 15);
        const int rB = wc * 64 + (lane & 15);
#pragma unroll
        for (int s = 0; s < 2; s++) {
            const int ca = ((s * 4 + (lane >> 4)) ^ (lane & 7)) * 8;
            short8 af[4], bzf[4], btf[4];
#pragma unroll
            for (int i = 0; i < 4; i++) af[i] = *(const short8*)(As + (rA + i * 16) * 64 + ca);
#pragma unroll
            for (int j = 0; j < 4; j++) {
                bzf[j] = *(const short8*)(Bzs + (rB + j * 16) * 64 + ca);
                btf[j] = *(const short8*)(Bts + (rB + j * 16) * 64 + ca);
            }
#pragma unroll
            for (int i = 0; i < 4; i++)
#pragma unroll
                for (int j = 0; j < 4; j++) {
                    accz[i][j] = __builtin_amdgcn_mfma_f32_16x16x32_bf16(af[i], bzf[j], accz[i][j], 0, 0, 0);
                    acct[i][j] = __builtin_amdgcn_mfma_f32_16x16x32_bf16(af[i], btf[j], acct[i][j], 0, 0, 0);
                }
        }
        __syncthreads();
    }

    float p2 = 0.f, p3 = 0.f;
    const int col = lane & 15;
    const int rowq = (lane >> 4) * 4;
#pragma unroll
    for (int j = 0; j < 4; j++) {
        int n = n0 + wc * 64 + j * 16 + col;
        float rdv = rdvt[fv * NOUT + n];
        float ebz = ebzt[fv * NOUT + n];
        float bt = bias_t[fv * NOUT + n];
        float gnv = Gn[n];
        float4 e4 = eta4[n];
#pragma unroll
        for (int i = 0; i < 4; i++) {
            int ebase = e0 + wr * 64 + i * 16 + rowq;
#pragma unroll
            for (int r = 0; r < 4; r++) {
                float z = fmaf(accz[i][j][r], rdv, ebz);
                float t = acct[i][j][r] + bt;
                p2 += z * t;
                p3 += z * z * gnv;
                float x = (z - e4.z) * e4.w;
                float ex = __expf(2.f * x);
                float th = 1.f - 2.f / (ex + 1.f);
                out[(fv * NE + ebase + r) * NOUT + n] = e4.x + e4.y * th;
            }
        }
    }
    for (int off = 32; off > 0; off >>= 1) {
        p2 += __shfl_down(p2, off);
        p3 += __shfl_down(p3, off);
    }
    __shared__ float r2[4], r3[4];
    if (lane == 0) { r2[wv] = p2; r3[wv] = p3; }
    __syncthreads();
    if (tid == 0) {
        int slot = (b & 31) * 8;
        atomicAdd(&p2slot[slot], r2[0] + r2[1] + r2[2] + r2[3]);
        atomicAdd(&p3slot[slot], r3[0] + r3[1] + r3[2] + r3[3]);
    }
}

// ---- k_final: sum slots, combine power terms ----
__global__ void k_final(const float* __restrict__ p1s, const float* __restrict__ p2s,
                        const float* __restrict__ p3s, const float* __restrict__ G,
                        float* __restrict__ out) {
    int t = threadIdx.x;  // 64
    float s1 = p1s[t * 8];
    float s2 = (t < 32) ? p2s[t * 8] : 0.f;
    float s3 = (t < 32) ? p3s[t * 8] : 0.f;
    for (int off = 32; off > 0; off >>= 1) {
        s1 += __shfl_down(s1, off);
        s2 += __shfl_down(s2, off);
        s3 += __shfl_down(s3, off);
    }
    if (t == 0) {
        float mp = (s1 + 16384.f * G[512] - 2.f * s2 + s3) * (1.f / 16384.f);
        out[8388608] = mp;
    }
}

extern "C" void kernel_launch(void* const* d_in, const int* in_sizes, int n_in,
                              void* d_out, int out_size, void* d_ws, size_t ws_size,
                              hipStream_t stream) {
    const float* a_prev = (const float*)d_in[0];
    const float* theta_ = (const float*)d_in[1];
    const float* coeff = (const float*)d_in[2];
    const float* noise = (const float*)d_in[3];
    const float* gumb = (const float*)d_in[4];
    float* out = (float*)d_out;
    char* w = (char*)d_ws;
    float* p1s = (float*)(w + WS_P1);
    float* p2s = (float*)(w + WS_P2);
    float* p3s = (float*)(w + WS_P3);
    float* G = (float*)(w + WS_G);
    float* Gn = (float*)(w + WS_GN);
    float4* eta4 = (float4*)(w + WS_ETA);
    float* bias_z = (float*)(w + WS_BIASZ);
    float* bias_t = (float*)(w + WS_BIAST);
    float* denomp = (float*)(w + WS_DENP);
    float* pmin = (float*)(w + WS_PMIN);
    float* psum = (float*)(w + WS_PSUM);
    u16* Abf = (u16*)(w + WS_ABF);
    u16* BzT = (u16*)(w + WS_BZT);
    u16* BtT = (u16*)(w + WS_BTT);
    float* rdvt = (float*)(w + WS_RDV);
    float* ebzt = (float*)(w + WS_EBZ);

    kA_part<<<16, 256, 0, stream>>>(theta_, pmin, psum, (float*)w);
    k_wmat3<<<dim3(8, 8, FV), 256, 0, stream>>>(theta_, pmin, psum, coeff, gumb, noise,
                                                BzT, BtT, bias_z, bias_t, denomp, G,
                                                Gn, eta4);
    k_prepA<<<2048, 256, 0, stream>>>(a_prev, G, denomp, noise, theta_, bias_z,
                                      Abf, p1s, rdvt, ebzt);
    k_gemm<<<512, 256, 0, stream>>>(Abf, BzT, BtT, rdvt, ebzt, bias_t, Gn, eta4,
                                    out, p2s, p3s);
    k_final<<<1, 64, 0, stream>>>(p1s, p2s, p3s, G, out);
}